// Round 12
// baseline (170.640 us; speedup 1.0000x reference)
//
#include <hip/hip_runtime.h>
#include <math.h>

constexpr int kM0 = 16, kM1 = 8, kDim = 40, kNW = 576;
constexpr int kNodes = 10000, kEdges = 160000;
constexpr int kCap = 96;  // bucket capacity; deg ~ Poisson(16), max deg << 96
constexpr int kNB = 24;   // nodes per k_node block (960 threads = 15 waves)

__device__ __forceinline__ float sspf(float x){
  float ax = fabsf(x);
  return fmaxf(x, 0.f) + log1pf(expf(-ax)) - 0.69314718055994531f;
}

__device__ __forceinline__ float dot8(const float* __restrict__ p, const float r[8]){
  return p[0]*r[0]+p[1]*r[1]+p[2]*r[2]+p[3]*r[3]
       + p[4]*r[4]+p[5]*r[5]+p[6]*r[6]+p[7]*r[7];
}

// ---------------- setup: zero cnt + transpose Wfc ----------------
__global__ void __launch_bounds__(1024) k_setup(
    const float* __restrict__ Wfc, float* __restrict__ WfcT, int* __restrict__ cnt){
  int t = blockIdx.x*1024 + threadIdx.x;
  if (t < kNodes) cnt[t] = 0;
  if (t < kNW){
    #pragma unroll
    for (int b=0;b<8;++b) WfcT[t*8+b] = Wfc[b*kNW + t];
  }
}

// ---------------- per-edge messages: 8 waves, 128 edges/block, 2 edges/lane ----------------
// Wave q owns w-slice q (2 scalar w, 1 vector w) for BOTH of its lane's edges —
// each wave-uniform WfcT s_load row feeds 2x the FMAs (halves s_load pressure).
// h lives in LDS (pad 41: stride mod 32 = 9, coprime -> 2 lanes/bank = free).
__global__ void __launch_bounds__(512) k_edge(
    const float* __restrict__ er, const float* __restrict__ esh,
    const int* __restrict__ esrc, const int* __restrict__ edst,
    const float* __restrict__ x, const float* __restrict__ W1s,
    const float* __restrict__ W1v, const float* __restrict__ WfcT,
    float* __restrict__ msg, int* __restrict__ cnt){
  __shared__ float sh_x[128][41];
  __shared__ float sh_h[128][41];
  __shared__ int   smp[128];
  int t = threadIdx.x;
  int lane = t & 63;
  int q = __builtin_amdgcn_readfirstlane(t >> 6);   // 0..7, wave-uniform
  int e0 = blockIdx.x*128;                          // exact grid: 1250*128

  // ---- waves 0,1: bucket-slot atomics (latency hides under staging) ----
  if (q < 2){
    int el = q*64 + lane;
    int dst = edst[e0 + el];
    int pos = atomicAdd(&cnt[dst], 1);
    smp[el] = (dst*kCap + pos)*kDim;
  }
  // ---- cooperative stage of x[src]: 128 edges x 10 float4 ----
  for (int idx = t; idx < 1280; idx += 512){
    int el = idx/10, c4 = idx - el*10;
    int src = esrc[e0 + el];
    const float4 v = *(const float4*)(x + (size_t)src*kDim + c4*4);
    float* d = &sh_x[el][c4*4];
    d[0]=v.x; d[1]=v.y; d[2]=v.z; d[3]=v.w;
  }
  __syncthreads();

  // ---- inline lin1: wave q computes h-col c = q+8k (uniform) for rows lane, lane+64 ----
  #pragma unroll
  for (int half=0; half<2; ++half){
    int row = half*64 + lane;
    #pragma unroll
    for (int k=0;k<5;++k){
      const int c = q + 8*k;
      float o;
      if (c < 16){
        float acc=0.f;
        #pragma unroll
        for (int u=0;u<16;++u) acc += sh_x[row][u]*W1s[u*16+c];
        o = acc*0.25f;                        // 1/sqrt(16)
      } else {
        int j = c-16; int v = j/3, i = j-3*v; // wave-uniform
        float acc=0.f;
        #pragma unroll
        for (int u=0;u<8;++u) acc += sh_x[row][16+u*3+i]*W1v[u*8+v];
        o = acc*0.35355339059327373f;         // 1/sqrt(8)
      }
      sh_h[row][c] = o;
    }
  }
  __syncthreads();

  const int eA = e0 + lane, eB = eA + 64;
  float rA[8], rB[8];
  { float4 a = *(const float4*)(er + (size_t)eA*8);
    float4 b = *(const float4*)(er + (size_t)eA*8 + 4);
    rA[0]=a.x;rA[1]=a.y;rA[2]=a.z;rA[3]=a.w;rA[4]=b.x;rA[5]=b.y;rA[6]=b.z;rA[7]=b.w; }
  { float4 a = *(const float4*)(er + (size_t)eB*8);
    float4 b = *(const float4*)(er + (size_t)eB*8 + 4);
    rB[0]=a.x;rB[1]=a.y;rB[2]=a.z;rB[3]=a.w;rB[4]=b.x;rB[5]=b.y;rB[6]=b.z;rB[7]=b.w; }
  float4 sA = *(const float4*)(esh + (size_t)eA*4);
  float4 sB = *(const float4*)(esh + (size_t)eB*4);
  const float* hA = sh_h[lane];
  const float* hB = sh_h[64 + lane];

  const int w0 = q*2;     // scalar w-range [w0, w0+2); vector w index = q
  float A00a=0.f,A00b=0.f,A11a=0.f,A11b=0.f,A01=0.f,Ax=0.f,Ay=0.f,Az=0.f;
  float B00a=0.f,B00b=0.f,B11a=0.f,B11b=0.f,B01=0.f,Bx=0.f,By=0.f,Bz=0.f;

  #pragma unroll
  for (int u=0;u<16;++u){
    float xa = hA[u], xb = hB[u];
    const float* p0 = WfcT + (size_t)(u*16 + w0)*8;
    A00a += xa*dot8(p0,rA);     B00a += xb*dot8(p0,rB);
    A00b += xa*dot8(p0+8,rA);   B00b += xb*dot8(p0+8,rB);
    const float* p1 = WfcT + (size_t)(256 + u*8 + q)*8;
    A01 += xa*dot8(p1,rA);      B01 += xb*dot8(p1,rB);
  }
  #pragma unroll
  for (int u=0;u<8;++u){
    float va0=hA[16+u*3], va1=hA[16+u*3+1], va2=hA[16+u*3+2];
    float vb0=hB[16+u*3], vb1=hB[16+u*3+1], vb2=hB[16+u*3+2];
    float auA = va0*sA.y + va1*sA.z + va2*sA.w;
    float auB = vb0*sB.y + vb1*sB.z + vb2*sB.w;
    const float* p3 = WfcT + (size_t)(448 + u*16 + w0)*8;
    A11a += auA*dot8(p3,rA);    B11a += auB*dot8(p3,rB);
    A11b += auA*dot8(p3+8,rA);  B11b += auB*dot8(p3+8,rB);
    const float* p2 = WfcT + (size_t)(384 + u*8 + q)*8;
    float aA = dot8(p2,rA), aB = dot8(p2,rB);
    Ax += va0*aA; Ay += va1*aA; Az += va2*aA;
    Bx += vb0*aB; By += vb1*aB; Bz += vb2*aB;
  }

  constexpr float cs00 = 0.0625f;               // inv2/(sqrt8*4)
  constexpr float cs11 = 0.05103103630798288f;  // 1/sqrt(384)
  constexpr float cv01 = 0.0625f;
  constexpr float cv10 = 0.08838834764831845f;  // inv2/8

  {
    float* mp = msg + smp[lane];
    *(float2*)(mp + w0) = make_float2(sA.x*A00a*cs00 + A11a*cs11,
                                      sA.x*A00b*cs00 + A11b*cs11);
    float va = A01*cv01, sc0 = sA.x*cv10;
    float* vp = mp + 16 + q*3;
    vp[0] = sA.y*va + Ax*sc0;
    vp[1] = sA.z*va + Ay*sc0;
    vp[2] = sA.w*va + Az*sc0;
  }
  {
    float* mp = msg + smp[64 + lane];
    *(float2*)(mp + w0) = make_float2(sB.x*B00a*cs00 + B11a*cs11,
                                      sB.x*B00b*cs00 + B11b*cs11);
    float vb = B01*cv01, sc0 = sB.x*cv10;
    float* vp = mp + 16 + q*3;
    vp[0] = sB.y*vb + Bx*sc0;
    vp[1] = sB.z*vb + By*sc0;
    vp[2] = sB.w*vb + Bz*sc0;
  }
}

// ---------------- fused gather + linear2 + gate + residual (R9 version) ----------------
// 960 threads = 24 nodes; gather mapping t -> (node, float4-chunk, k-phase) = 24*10*4.
__global__ void __launch_bounds__(960) k_node(
    const float* __restrict__ x, const float* __restrict__ msg,
    const int* __restrict__ cnt,
    const float* __restrict__ W2s, const float* __restrict__ W2v,
    const float* __restrict__ R00, const float* __restrict__ R01,
    const float* __restrict__ R10, const float* __restrict__ R11,
    float* __restrict__ out){
  __shared__ float sR00[4096], sR01[1024], sR10[1024], sR11[1024];
  __shared__ float sW2s[256], sW2v[64];
  __shared__ float sx[kNB][40], sa[kNB][40];
  __shared__ float4 sred[kNB][4][10];
  int t = threadIdx.x;
  for (int i=t; i<1024; i+=960) ((float4*)sR00)[i] = ((const float4*)R00)[i];
  if (t < 256){
    ((float4*)sR01)[t] = ((const float4*)R01)[t];
    ((float4*)sR10)[t] = ((const float4*)R10)[t];
    ((float4*)sR11)[t] = ((const float4*)R11)[t];
  }
  if (t >= 256 && t < 320) ((float4*)sW2s)[t-256] = ((const float4*)W2s)[t-256];
  if (t >= 320 && t < 336) ((float4*)sW2v)[t-320] = ((const float4*)W2v)[t-320];
  int nb = blockIdx.x*kNB;
  {
    int ns = t/40; int rem = t - ns*40; int kq = rem/10; int c4 = rem - kq*10;
    int n = nb + ns;
    float4 acc = make_float4(0.f,0.f,0.f,0.f);
    if (n < kNodes){
      int deg = cnt[n];
      const float* bp = msg + (size_t)n*kCap*kDim + c4*4;
      for (int k=kq; k<deg; k+=4){
        const float4 v = *(const float4*)(bp + (size_t)k*kDim);
        acc.x+=v.x; acc.y+=v.y; acc.z+=v.z; acc.w+=v.w;
      }
    }
    sred[ns][kq][c4] = acc;
  }
  __syncthreads();
  if (t < kNB*10){
    int ns = t/10, c4 = t - ns*10, n = nb+ns;
    float4 a0 = sred[ns][0][c4], a1 = sred[ns][1][c4];
    float4 a2 = sred[ns][2][c4], a3 = sred[ns][3][c4];
    sa[ns][c4*4+0] = (a0.x+a1.x+a2.x+a3.x)*0.25f;   // fold 1/deg = 1/4
    sa[ns][c4*4+1] = (a0.y+a1.y+a2.y+a3.y)*0.25f;
    sa[ns][c4*4+2] = (a0.z+a1.z+a2.z+a3.z)*0.25f;
    sa[ns][c4*4+3] = (a0.w+a1.w+a2.w+a3.w)*0.25f;
    float4 xv = (n < kNodes) ? *(const float4*)(x + (size_t)n*kDim + c4*4)
                             : make_float4(0.f,0.f,0.f,0.f);
    sx[ns][c4*4+0]=xv.x; sx[ns][c4*4+1]=xv.y; sx[ns][c4*4+2]=xv.z; sx[ns][c4*4+3]=xv.w;
  }
  __syncthreads();
  if (t < kNB*16){
    int ns = t>>4, w = t&15, n = nb+ns;
    const float* ap = sa[ns];
    const float* xp = sx[ns];
    float hsum = 0.f;
    #pragma unroll
    for (int u=0;u<16;++u) hsum += ap[u]*sW2s[u*16+w];
    hsum *= 0.25f;                 // 1/sqrt(16)
    float nrm = sqrtf(hsum*hsum + 1e-16f);
    float val = hsum/nrm*sspf(nrm);
    float xs[16];
    #pragma unroll
    for (int v=0;v<16;++v) xs[v] = xp[v];
    float r0 = 0.f;
    #pragma unroll
    for (int u=0;u<16;++u){
      float tacc = 0.f;
      #pragma unroll
      for (int v=0;v<16;++v) tacc += xs[v]*sR00[(u*16+v)*16+w];
      r0 += xs[u]*tacc;
    }
    float xv[24];
    #pragma unroll
    for (int c2=0;c2<24;++c2) xv[c2] = xp[16+c2];
    float r1 = 0.f;
    #pragma unroll
    for (int u=0;u<8;++u){
      #pragma unroll
      for (int v=0;v<8;++v){
        float dot = xv[u*3]*xv[v*3] + xv[u*3+1]*xv[v*3+1] + xv[u*3+2]*xv[v*3+2];
        r1 += dot*sR11[(u*8+v)*16+w];
      }
    }
    if (n < kNodes)
      out[(size_t)n*kDim + w] = val + 0.04419417382415922f*r0 + 0.05103103630798288f*r1;
  } else if (t < kNB*16 + kNB*24) {
    int t2 = t - kNB*16;
    int ns = t2/24, cc = t2 - ns*24, w = cc/3, i = cc - w*3, n = nb+ns;
    const float* ap = sa[ns] + 16;
    const float* xp = sx[ns];
    float h0=0.f,h1=0.f,h2=0.f;
    #pragma unroll
    for (int u=0;u<8;++u){
      float wv = sW2v[u*8+w];
      h0 += ap[u*3+0]*wv; h1 += ap[u*3+1]*wv; h2 += ap[u*3+2]*wv;
    }
    const float sc = 0.35355339059327373f;   // 1/sqrt(8)
    h0*=sc; h1*=sc; h2*=sc;
    float nv = sqrtf(h0*h0+h1*h1+h2*h2 + 1e-16f);
    float hi = (i==0)?h0:((i==1)?h1:h2);
    float val = hi/nv*sspf(nv);
    float xs[16];
    #pragma unroll
    for (int v=0;v<16;++v) xs[v] = xp[v];
    float xvi[8];
    #pragma unroll
    for (int v=0;v<8;++v) xvi[v] = xp[16+v*3+i];
    float racc = 0.f;
    #pragma unroll
    for (int u=0;u<16;++u){
      float tacc=0.f;
      #pragma unroll
      for (int v=0;v<8;++v) tacc += xvi[v]*sR01[(u*8+v)*8+w];
      racc += xs[u]*tacc;
    }
    #pragma unroll
    for (int u=0;u<8;++u){
      float tacc=0.f;
      #pragma unroll
      for (int v=0;v<16;++v) tacc += xs[v]*sR10[(u*16+v)*8+w];
      racc += xvi[u]*tacc;
    }
    if (n < kNodes)
      out[(size_t)n*kDim + 16 + cc] = val + 0.0625f*racc;   // inv2/sqrt(128)
  }
}

extern "C" void kernel_launch(void* const* d_in, const int* in_sizes, int n_in,
                              void* d_out, int out_size, void* d_ws, size_t ws_size,
                              hipStream_t stream){
  const float* x   = (const float*)d_in[0];
  const float* er  = (const float*)d_in[1];
  const float* esh = (const float*)d_in[2];
  const int*   esrc= (const int*)d_in[3];
  const int*   edst= (const int*)d_in[4];
  const float* W1s = (const float*)d_in[6];
  const float* W1v = (const float*)d_in[7];
  const float* Wfc = (const float*)d_in[8];
  const float* W2s = (const float*)d_in[9];
  const float* W2v = (const float*)d_in[10];
  const float* R00 = (const float*)d_in[11];
  const float* R01 = (const float*)d_in[12];
  const float* R10 = (const float*)d_in[13];
  const float* R11 = (const float*)d_in[14];
  float* out = (float*)d_out;

  // ws layout (16B-aligned blocks)
  char* wsb = (char*)d_ws;
  float* msg  = (float*)wsb;                                     // 10000*96*40 f (153.6 MB)
  float* WfcT = msg + (size_t)kNodes*kCap*kDim;                  // 4,608 f
  int*   cnt  = (int*)(WfcT + (size_t)kNW*8);                    // 10,000

  k_setup<<<10, 1024, 0, stream>>>(Wfc, WfcT, cnt);
  k_edge<<<kEdges/128, 512, 0, stream>>>(er, esh, esrc, edst, x, W1s, W1v, WfcT, msg, cnt);
  k_node<<<(kNodes+kNB-1)/kNB, 960, 0, stream>>>(x, msg, cnt, W2s, W2v, R00, R01, R10, R11, out);
}

// Round 13
// 155.017 us; speedup vs baseline: 1.1008x; 1.1008x over previous
//
#include <hip/hip_runtime.h>
#include <math.h>

constexpr int kM0 = 16, kM1 = 8, kDim = 40, kNW = 576;
constexpr int kNodes = 10000, kEdges = 160000;
constexpr int kCap = 96;  // bucket capacity; deg ~ Poisson(16), max deg << 96
constexpr int kNB = 24;   // nodes per k_node block (960 threads = 15 waves)

__device__ __forceinline__ float sspf(float x){
  float ax = fabsf(x);
  return fmaxf(x, 0.f) + log1pf(expf(-ax)) - 0.69314718055994531f;
}

// float -> bf16 (round to nearest even), raw ushort
__device__ __forceinline__ ushort f2bf(float f){
  unsigned u = __float_as_uint(f);
  u += 0x7fffu + ((u >> 16) & 1u);
  return (ushort)(u >> 16);
}
__device__ __forceinline__ float bflo(unsigned v){ return __uint_as_float(v << 16); }
__device__ __forceinline__ float bfhi(unsigned v){ return __uint_as_float(v & 0xffff0000u); }

// ---------------- setup: zero cnt + transpose Wfc ----------------
__global__ void __launch_bounds__(1024) k_setup(
    const float* __restrict__ Wfc, float* __restrict__ WfcT, int* __restrict__ cnt){
  int t = blockIdx.x*1024 + threadIdx.x;
  if (t < kNodes) cnt[t] = 0;
  if (t < kNW){
    #pragma unroll
    for (int b=0;b<8;++b) WfcT[t*8+b] = Wfc[b*kNW + t];
  }
}

// ---------------- per-edge messages: 8 waves per 64-edge group (R9 structure) ----------------
// Absorbs lin1 + bucket-slot atomic; wave q owns w-slice q; WfcT/W1 wave-uniform -> s_load.
// Messages stored as bf16 (40 x 2B = 80B rows).
__global__ void __launch_bounds__(512) k_edge(
    const float* __restrict__ er, const float* __restrict__ esh,
    const int* __restrict__ esrc, const int* __restrict__ edst,
    const float* __restrict__ x, const float* __restrict__ W1s,
    const float* __restrict__ W1v, const float* __restrict__ WfcT,
    ushort* __restrict__ msg, int* __restrict__ cnt){
  __shared__ float sh_x[64][41];
  __shared__ float sh_h[64][41];
  __shared__ int   smp[64];
  int t = threadIdx.x;
  int lane = t & 63;
  int q = __builtin_amdgcn_readfirstlane(t >> 6);   // 0..7, wave-uniform
  int e0 = blockIdx.x*64;                           // exact grid: 2500*64

  // ---- wave 0: bucket-slot atomic (latency hides under staging) ----
  int myoff = 0;
  if (q == 0){
    int dst = edst[e0 + lane];
    int pos = atomicAdd(&cnt[dst], 1);
    myoff = (dst*kCap + pos)*kDim;
  }
  // ---- cooperative stage of x[src]: 64 edges x 10 float4 ----
  for (int idx = t; idx < 640; idx += 512){
    int el = idx/10, c4 = idx - el*10;
    int src = esrc[e0 + el];
    const float4 v = *(const float4*)(x + (size_t)src*kDim + c4*4);
    float* d = &sh_x[el][c4*4];
    d[0]=v.x; d[1]=v.y; d[2]=v.z; d[3]=v.w;
  }
  if (q == 0) smp[lane] = myoff;
  __syncthreads();

  // ---- inline lin1: wave q computes h-col c = q+8k (uniform) for el=lane ----
  {
    #pragma unroll
    for (int k=0;k<5;++k){
      const int c = q + 8*k;
      float o;
      if (c < 16){
        float acc=0.f;
        #pragma unroll
        for (int u=0;u<16;++u) acc += sh_x[lane][u]*W1s[u*16+c];
        o = acc*0.25f;                        // 1/sqrt(16)
      } else {
        int j = c-16; int v = j/3, i = j-3*v; // wave-uniform
        float acc=0.f;
        #pragma unroll
        for (int u=0;u<8;++u) acc += sh_x[lane][16+u*3+i]*W1v[u*8+v];
        o = acc*0.35355339059327373f;         // 1/sqrt(8)
      }
      sh_h[lane][c] = o;
    }
  }
  __syncthreads();

  int e = e0 + lane;
  float4 ra = *(const float4*)(er + (size_t)e*8);
  float4 rb = *(const float4*)(er + (size_t)e*8 + 4);
  const float r0=ra.x,r1=ra.y,r2=ra.z,r3=ra.w,r4=rb.x,r5=rb.y,r6=rb.z,r7=rb.w;
  float4 s4 = *(const float4*)(esh + (size_t)e*4);
  const float* hl = sh_h[lane];

#define DOT8(p) ((p)[0]*r0+(p)[1]*r1+(p)[2]*r2+(p)[3]*r3+(p)[4]*r4+(p)[5]*r5+(p)[6]*r6+(p)[7]*r7)

  const int w0 = q*2;     // scalar w-range [w0, w0+2); vector w index = q
  float t00a=0.f, t00b=0.f, t11a=0.f, t11b=0.f;
  float t01=0.f, tx=0.f, ty=0.f, tz=0.f;

  #pragma unroll
  for (int u=0;u<16;++u){
    float xu = hl[u];
    const float* p0 = WfcT + (size_t)(u*16 + w0)*8;
    t00a += xu*DOT8(p0);
    t00b += xu*DOT8(p0 + 8);
    const float* p1 = WfcT + (size_t)(256 + u*8 + q)*8;
    t01 += xu*DOT8(p1);
  }
  #pragma unroll
  for (int u=0;u<8;++u){
    float v0=hl[16+u*3], v1=hl[16+u*3+1], v2=hl[16+u*3+2];
    float au = v0*s4.y + v1*s4.z + v2*s4.w;
    const float* p3 = WfcT + (size_t)(448 + u*16 + w0)*8;
    t11a += au*DOT8(p3);
    t11b += au*DOT8(p3 + 8);
    const float* p2 = WfcT + (size_t)(384 + u*8 + q)*8;
    float a = DOT8(p2);
    tx += v0*a; ty += v1*a; tz += v2*a;
  }
#undef DOT8

  constexpr float cs00 = 0.0625f;               // inv2/(sqrt8*4)
  constexpr float cs11 = 0.05103103630798288f;  // 1/sqrt(384)
  constexpr float cv01 = 0.0625f;
  constexpr float cv10 = 0.08838834764831845f;  // inv2/8

  ushort* rowp = msg + (size_t)smp[lane]*2/2;   // element offset already *kDim
  rowp = msg + (size_t)smp[lane];               // (smp is in 40-element rows)
  // scalar pair -> one uint at uint-index q (row base is 80B-aligned)
  unsigned packed = (unsigned)f2bf(s4.x*t00a*cs00 + t11a*cs11)
                  | ((unsigned)f2bf(s4.x*t00b*cs00 + t11b*cs11) << 16);
  ((unsigned*)rowp)[q] = packed;
  // vector triple at element offset 16 + 3q (3 ushort stores)
  float va = t01*cv01, sc0 = s4.x*cv10;
  rowp[16 + 3*q + 0] = f2bf(s4.y*va + tx*sc0);
  rowp[16 + 3*q + 1] = f2bf(s4.z*va + ty*sc0);
  rowp[16 + 3*q + 2] = f2bf(s4.w*va + tz*sc0);
}

// ---------------- fused gather + linear2 + gate + residual ----------------
// 960 threads = 24 nodes; bf16 gather mapping t -> (node 24, uint-col 20, k-phase 2).
__global__ void __launch_bounds__(960) k_node(
    const float* __restrict__ x, const ushort* __restrict__ msg,
    const int* __restrict__ cnt,
    const float* __restrict__ W2s, const float* __restrict__ W2v,
    const float* __restrict__ R00, const float* __restrict__ R01,
    const float* __restrict__ R10, const float* __restrict__ R11,
    float* __restrict__ out){
  __shared__ float sR00[4096], sR01[1024], sR10[1024], sR11[1024];
  __shared__ float sW2s[256], sW2v[64];
  __shared__ float sx[kNB][40], sa[kNB][40];
  __shared__ float2 sred[kNB][2][20];
  int t = threadIdx.x;
  for (int i=t; i<1024; i+=960) ((float4*)sR00)[i] = ((const float4*)R00)[i];
  if (t < 256){
    ((float4*)sR01)[t] = ((const float4*)R01)[t];
    ((float4*)sR10)[t] = ((const float4*)R10)[t];
    ((float4*)sR11)[t] = ((const float4*)R11)[t];
  }
  if (t >= 256 && t < 320) ((float4*)sW2s)[t-256] = ((const float4*)W2s)[t-256];
  if (t >= 320 && t < 336) ((float4*)sW2v)[t-320] = ((const float4*)W2v)[t-320];
  int nb = blockIdx.x*kNB;
  // ---- gather: each thread sums one uint-column (2 bf16) over its k-phase ----
  {
    int ns = t/40; int rem = t - ns*40; int kq = rem/20; int c2 = rem - kq*20;
    int n = nb + ns;
    float lo0=0.f,hi0=0.f,lo1=0.f,hi1=0.f;
    if (n < kNodes){
      int deg = cnt[n];
      const unsigned* bp = (const unsigned*)msg + (size_t)n*kCap*20 + c2;
      int k = kq;
      for (; k+2 < deg; k += 4){
        unsigned va = bp[(size_t)k*20];
        unsigned vb = bp[(size_t)(k+2)*20];
        lo0 += bflo(va); hi0 += bfhi(va);
        lo1 += bflo(vb); hi1 += bfhi(vb);
      }
      if (k < deg){
        unsigned va = bp[(size_t)k*20];
        lo0 += bflo(va); hi0 += bfhi(va);
      }
    }
    sred[ns][kq][c2] = make_float2(lo0+lo1, hi0+hi1);
  }
  __syncthreads();
  if (t < kNB*20){
    int ns = t/20, c2 = t - ns*20, n = nb+ns;
    float2 a = sred[ns][0][c2], b = sred[ns][1][c2];
    sa[ns][c2*2]   = (a.x+b.x)*0.25f;          // fold 1/deg = 1/4
    sa[ns][c2*2+1] = (a.y+b.y)*0.25f;
    if (n < kNodes){
      float2 xv = *(const float2*)(x + (size_t)n*kDim + c2*2);
      sx[ns][c2*2] = xv.x; sx[ns][c2*2+1] = xv.y;
    } else {
      sx[ns][c2*2] = 0.f; sx[ns][c2*2+1] = 0.f;
    }
  }
  __syncthreads();
  if (t < kNB*16){
    int ns = t>>4, w = t&15, n = nb+ns;
    const float* ap = sa[ns];
    const float* xp = sx[ns];
    float hsum = 0.f;
    #pragma unroll
    for (int u=0;u<16;++u) hsum += ap[u]*sW2s[u*16+w];
    hsum *= 0.25f;                 // 1/sqrt(16)
    float nrm = sqrtf(hsum*hsum + 1e-16f);
    float val = hsum/nrm*sspf(nrm);
    float xs[16];
    #pragma unroll
    for (int v=0;v<16;++v) xs[v] = xp[v];
    float r0 = 0.f;
    #pragma unroll
    for (int u=0;u<16;++u){
      float tacc = 0.f;
      #pragma unroll
      for (int v=0;v<16;++v) tacc += xs[v]*sR00[(u*16+v)*16+w];
      r0 += xs[u]*tacc;
    }
    float xv[24];
    #pragma unroll
    for (int c2=0;c2<24;++c2) xv[c2] = xp[16+c2];
    float r1 = 0.f;
    #pragma unroll
    for (int u=0;u<8;++u){
      #pragma unroll
      for (int v=0;v<8;++v){
        float dot = xv[u*3]*xv[v*3] + xv[u*3+1]*xv[v*3+1] + xv[u*3+2]*xv[v*3+2];
        r1 += dot*sR11[(u*8+v)*16+w];
      }
    }
    if (n < kNodes)
      out[(size_t)n*kDim + w] = val + 0.04419417382415922f*r0 + 0.05103103630798288f*r1;
  } else if (t < kNB*16 + kNB*24) {
    int t2 = t - kNB*16;
    int ns = t2/24, cc = t2 - ns*24, w = cc/3, i = cc - w*3, n = nb+ns;
    const float* ap = sa[ns] + 16;
    const float* xp = sx[ns];
    float h0=0.f,h1=0.f,h2=0.f;
    #pragma unroll
    for (int u=0;u<8;++u){
      float wv = sW2v[u*8+w];
      h0 += ap[u*3+0]*wv; h1 += ap[u*3+1]*wv; h2 += ap[u*3+2]*wv;
    }
    const float sc = 0.35355339059327373f;   // 1/sqrt(8)
    h0*=sc; h1*=sc; h2*=sc;
    float nv = sqrtf(h0*h0+h1*h1+h2*h2 + 1e-16f);
    float hi = (i==0)?h0:((i==1)?h1:h2);
    float val = hi/nv*sspf(nv);
    float xs[16];
    #pragma unroll
    for (int v=0;v<16;++v) xs[v] = xp[v];
    float xvi[8];
    #pragma unroll
    for (int v=0;v<8;++v) xvi[v] = xp[16+v*3+i];
    float racc = 0.f;
    #pragma unroll
    for (int u=0;u<16;++u){
      float tacc=0.f;
      #pragma unroll
      for (int v=0;v<8;++v) tacc += xvi[v]*sR01[(u*8+v)*8+w];
      racc += xs[u]*tacc;
    }
    #pragma unroll
    for (int u=0;u<8;++u){
      float tacc=0.f;
      #pragma unroll
      for (int v=0;v<16;++v) tacc += xs[v]*sR10[(u*16+v)*8+w];
      racc += xvi[u]*tacc;
    }
    if (n < kNodes)
      out[(size_t)n*kDim + 16 + cc] = val + 0.0625f*racc;   // inv2/sqrt(128)
  }
}

extern "C" void kernel_launch(void* const* d_in, const int* in_sizes, int n_in,
                              void* d_out, int out_size, void* d_ws, size_t ws_size,
                              hipStream_t stream){
  const float* x   = (const float*)d_in[0];
  const float* er  = (const float*)d_in[1];
  const float* esh = (const float*)d_in[2];
  const int*   esrc= (const int*)d_in[3];
  const int*   edst= (const int*)d_in[4];
  const float* W1s = (const float*)d_in[6];
  const float* W1v = (const float*)d_in[7];
  const float* Wfc = (const float*)d_in[8];
  const float* W2s = (const float*)d_in[9];
  const float* W2v = (const float*)d_in[10];
  const float* R00 = (const float*)d_in[11];
  const float* R01 = (const float*)d_in[12];
  const float* R10 = (const float*)d_in[13];
  const float* R11 = (const float*)d_in[14];
  float* out = (float*)d_out;

  // ws layout (16B-aligned blocks)
  char* wsb = (char*)d_ws;
  ushort* msg = (ushort*)wsb;                                    // 10000*96*40 bf16 (76.8 MB)
  float* WfcT = (float*)(wsb + (size_t)kNodes*kCap*kDim*2);      // 4,608 f
  int*   cnt  = (int*)(WfcT + (size_t)kNW*8);                    // 10,000

  k_setup<<<10, 1024, 0, stream>>>(Wfc, WfcT, cnt);
  k_edge<<<kEdges/64, 512, 0, stream>>>(er, esh, esrc, edst, x, W1s, W1v, WfcT, msg, cnt);
  k_node<<<(kNodes+kNB-1)/kNB, 960, 0, stream>>>(x, msg, cnt, W2s, W2v, R00, R01, R10, R11, out);
}

// Round 14
// 133.920 us; speedup vs baseline: 1.2742x; 1.1575x over previous
//
#include <hip/hip_runtime.h>
#include <hip/hip_bf16.h>
#include <math.h>

constexpr int kM0 = 16, kM1 = 8, kDim = 40, kNW = 576;
constexpr int kNodes = 10000, kEdges = 160000;
constexpr int kCap = 96;  // bucket capacity; deg ~ Poisson(16), max deg << 96
constexpr int kNB = 24;   // nodes per k_node block (960 threads = 15 waves)

typedef __attribute__((ext_vector_type(8))) short short8;
typedef __attribute__((ext_vector_type(4))) float f32x4;

__device__ __forceinline__ float sspf(float x){
  float ax = fabsf(x);
  return fmaxf(x, 0.f) + log1pf(expf(-ax)) - 0.69314718055994531f;
}

__device__ __forceinline__ short bfbits(float f){   // f32 -> bf16 bits (RNE)
  unsigned u = __float_as_uint(f);
  u += 0x7fffu + ((u >> 16) & 1u);
  return (short)(u >> 16);
}

// ---------------- setup: zero cnt + build static B-fragments ----------------
// 12 fragment-sets (short8 per lane): 0-3 W00(K=128), 4-7 W01(K=128, cols>=8 zero),
// 8-9 W11(K=64), 10-11 W10(K=64, cols>=8 zero).
// B-frag layout: lane l -> col n=l&15, k = kbase + (l>>4)*8 + j;  k=(u,b): u=k>>3, b=k&7.
__global__ void __launch_bounds__(1024) k_setup(
    const float* __restrict__ Wfc, short* __restrict__ Bf, int* __restrict__ cnt){
  int t = blockIdx.x*1024 + threadIdx.x;
  if (t < kNodes) cnt[t] = 0;
  if (t < 12*64*8){
    int s = t >> 9, l = (t >> 3) & 63, j = t & 7;
    int n = l & 15, kg = l >> 4;
    float val = 0.f;
    if (s < 4){                       // W00[k, n] = Wfc[b, u*16+n]
      int k = s*32 + kg*8 + j, u = k>>3, b = k&7;
      val = Wfc[b*kNW + u*16 + n];
    } else if (s < 8){                // W01[k, n<8] = Wfc[b, 256 + u*8 + n]
      int k = (s-4)*32 + kg*8 + j, u = k>>3, b = k&7;
      if (n < 8) val = Wfc[b*kNW + 256 + u*8 + n];
    } else if (s < 10){               // W11[k64, n] = Wfc[b, 448 + u*16 + n]
      int k = (s-8)*32 + kg*8 + j, u = k>>3, b = k&7;
      val = Wfc[b*kNW + 448 + u*16 + n];
    } else {                          // W10[k64, n<8] = Wfc[b, 384 + u*8 + n]
      int k = (s-10)*32 + kg*8 + j, u = k>>3, b = k&7;
      if (n < 8) val = Wfc[b*kNW + 384 + u*8 + n];
    }
    Bf[t] = bfbits(val);
  }
}

// ---------------- per-edge messages via MFMA ----------------
// 256 thr = 4 waves, 64 edges/block; wave wv owns edges [16wv, 16wv+16).
// Per wave: D00=F0*W00 (4 mfma), D01=F0*W01 (4), D11=F1*W11 (2), D10_i=F2i*W10 (6).
// F0[e,k]=hs[e,u]*r[e,b]; F1=au*r (au=hv.sh1); F2i=hv_i*r.  Scales at C-phase.
__global__ void __launch_bounds__(256, 4) k_edge(
    const float* __restrict__ er, const float* __restrict__ esh,
    const int* __restrict__ esrc, const int* __restrict__ edst,
    const float* __restrict__ x, const float* __restrict__ W1s,
    const float* __restrict__ W1v, const short* __restrict__ Bf,
    float* __restrict__ msg, int* __restrict__ cnt){
  __shared__ float sh_x[64][41];
  __shared__ float sh_h[64][41];
  __shared__ float sh_r[64][12];
  __shared__ float sh_s[64][4];
  __shared__ float sh_au[64][9];
  __shared__ int   smp[64];
  int t = threadIdx.x, lane = t & 63;
  int wv = __builtin_amdgcn_readfirstlane(t >> 6);   // 0..3
  int e0 = blockIdx.x*64;                            // exact grid: 2500*64

  if (wv == 0){                                      // bucket-slot atomics
    int dst = edst[e0 + lane];
    int pos = atomicAdd(&cnt[dst], 1);
    smp[lane] = (dst*kCap + pos)*kDim;
  }
  for (int idx = t; idx < 640; idx += 256){          // stage x[src]
    int el = idx/10, c4 = idx - el*10;
    float4 v = *(const float4*)(x + (size_t)esrc[e0+el]*kDim + c4*4);
    float* d = &sh_x[el][c4*4];
    d[0]=v.x; d[1]=v.y; d[2]=v.z; d[3]=v.w;
  }
  if (t < 128){                                      // stage r (f32)
    int e = t>>1, hf = t&1;
    float4 v = *(const float4*)(er + (size_t)(e0+e)*8 + hf*4);
    *(float4*)&sh_r[e][hf*4] = v;
  } else if (t < 192){                               // stage sh
    int e = t-128;
    float4 v = *(const float4*)(esh + (size_t)(e0+e)*4);
    *(float4*)&sh_s[e][0] = v;
  }
  __syncthreads();
  // lin1: wave wv computes h-col c = wv+4k (wave-uniform) for edge=lane
  #pragma unroll
  for (int k=0;k<10;++k){
    const int c = wv + 4*k;
    float o;
    if (c < 16){
      float acc=0.f;
      #pragma unroll
      for (int u=0;u<16;++u) acc += sh_x[lane][u]*W1s[u*16+c];
      o = acc*0.25f;                        // 1/sqrt(16)
    } else {
      int j = c-16; int v = j/3, i = j-3*v;
      float acc=0.f;
      #pragma unroll
      for (int u=0;u<8;++u) acc += sh_x[lane][16+u*3+i]*W1v[u*8+v];
      o = acc*0.35355339059327373f;         // 1/sqrt(8)
    }
    sh_h[lane][c] = o;
  }
  __syncthreads();
  for (int idx = t; idx < 512; idx += 256){          // au[e][u] = hv[u].sh1
    int e = idx>>3, u = idx&7;
    sh_au[e][u] = sh_h[e][16+u*3+0]*sh_s[e][1]
                + sh_h[e][16+u*3+1]*sh_s[e][2]
                + sh_h[e][16+u*3+2]*sh_s[e][3];
  }
  __syncthreads();

  // ---- MFMA phase ----
  const int n = lane & 15, kg = lane >> 4;
  const int erow = wv*16 + n;                        // A row = edge (lane&15 of tile)
  float4 ra = *(const float4*)&sh_r[erow][0];
  float4 rb = *(const float4*)&sh_r[erow][4];
  float rr[8] = {ra.x,ra.y,ra.z,ra.w,rb.x,rb.y,rb.z,rb.w};
  const short8* Bp = (const short8*)Bf;
  short8 b00[4], b01[4], b11[2], b10[2];
  #pragma unroll
  for (int m=0;m<4;++m){ b00[m] = Bp[m*64+lane]; b01[m] = Bp[(4+m)*64+lane]; }
  #pragma unroll
  for (int m=0;m<2;++m){ b11[m] = Bp[(8+m)*64+lane]; b10[m] = Bp[(10+m)*64+lane]; }

  f32x4 d00 = {0.f,0.f,0.f,0.f}, d01 = {0.f,0.f,0.f,0.f}, d11 = {0.f,0.f,0.f,0.f};
  f32x4 d10_0 = {0.f,0.f,0.f,0.f}, d10_1 = {0.f,0.f,0.f,0.f}, d10_2 = {0.f,0.f,0.f,0.f};

  #pragma unroll
  for (int m=0;m<4;++m){                             // F0 = hs[u]*r[b], K=128
    float hsv = sh_h[erow][4*m + kg];
    short8 a;
    #pragma unroll
    for (int j=0;j<8;++j) a[j] = bfbits(hsv*rr[j]);
    d00 = __builtin_amdgcn_mfma_f32_16x16x32_bf16(a, b00[m], d00, 0, 0, 0);
    d01 = __builtin_amdgcn_mfma_f32_16x16x32_bf16(a, b01[m], d01, 0, 0, 0);
  }
  #pragma unroll
  for (int m=0;m<2;++m){                             // F1 = au[u]*r[b], K=64
    float auv = sh_au[erow][4*m + kg];
    short8 a;
    #pragma unroll
    for (int j=0;j<8;++j) a[j] = bfbits(auv*rr[j]);
    d11 = __builtin_amdgcn_mfma_f32_16x16x32_bf16(a, b11[m], d11, 0, 0, 0);
  }
  #pragma unroll
  for (int m=0;m<2;++m){                             // F2i = hv[u,i]*r[b], K=64
    float h0v = sh_h[erow][16 + (4*m+kg)*3 + 0];
    float h1v = sh_h[erow][16 + (4*m+kg)*3 + 1];
    float h2v = sh_h[erow][16 + (4*m+kg)*3 + 2];
    short8 a0, a1, a2;
    #pragma unroll
    for (int j=0;j<8;++j){
      a0[j] = bfbits(h0v*rr[j]); a1[j] = bfbits(h1v*rr[j]); a2[j] = bfbits(h2v*rr[j]);
    }
    d10_0 = __builtin_amdgcn_mfma_f32_16x16x32_bf16(a0, b10[m], d10_0, 0, 0, 0);
    d10_1 = __builtin_amdgcn_mfma_f32_16x16x32_bf16(a1, b10[m], d10_1, 0, 0, 0);
    d10_2 = __builtin_amdgcn_mfma_f32_16x16x32_bf16(a2, b10[m], d10_2, 0, 0, 0);
  }

  constexpr float cs00 = 0.0625f;               // inv2/(sqrt8*4)
  constexpr float cs11 = 0.05103103630798288f;  // 1/sqrt(384)
  constexpr float cv01 = 0.0625f;
  constexpr float cv10 = 0.08838834764831845f;  // inv2/8
  // D: lane holds col n, rows kg*4+reg (within the wave's 16-edge tile)
  #pragma unroll
  for (int reg=0;reg<4;++reg){
    int el = wv*16 + kg*4 + reg;
    float* mp = msg + smp[el];
    float s0 = sh_s[el][0];
    mp[n] = s0*cs00*d00[reg] + cs11*d11[reg];
    if (n < 8){
      float dv = cv01*d01[reg], sv = s0*cv10;
      mp[16+3*n+0] = sh_s[el][1]*dv + sv*d10_0[reg];
      mp[16+3*n+1] = sh_s[el][2]*dv + sv*d10_1[reg];
      mp[16+3*n+2] = sh_s[el][3]*dv + sv*d10_2[reg];
    }
  }
}

// ---------------- fused gather + linear2 + gate + residual (R9 version) ----------------
__global__ void __launch_bounds__(960) k_node(
    const float* __restrict__ x, const float* __restrict__ msg,
    const int* __restrict__ cnt,
    const float* __restrict__ W2s, const float* __restrict__ W2v,
    const float* __restrict__ R00, const float* __restrict__ R01,
    const float* __restrict__ R10, const float* __restrict__ R11,
    float* __restrict__ out){
  __shared__ float sR00[4096], sR01[1024], sR10[1024], sR11[1024];
  __shared__ float sW2s[256], sW2v[64];
  __shared__ float sx[kNB][40], sa[kNB][40];
  __shared__ float4 sred[kNB][4][10];
  int t = threadIdx.x;
  for (int i=t; i<1024; i+=960) ((float4*)sR00)[i] = ((const float4*)R00)[i];
  if (t < 256){
    ((float4*)sR01)[t] = ((const float4*)R01)[t];
    ((float4*)sR10)[t] = ((const float4*)R10)[t];
    ((float4*)sR11)[t] = ((const float4*)R11)[t];
  }
  if (t >= 256 && t < 320) ((float4*)sW2s)[t-256] = ((const float4*)W2s)[t-256];
  if (t >= 320 && t < 336) ((float4*)sW2v)[t-320] = ((const float4*)W2v)[t-320];
  int nb = blockIdx.x*kNB;
  {
    int ns = t/40; int rem = t - ns*40; int kq = rem/10; int c4 = rem - kq*10;
    int n = nb + ns;
    float4 acc = make_float4(0.f,0.f,0.f,0.f);
    if (n < kNodes){
      int deg = cnt[n];
      const float* bp = msg + (size_t)n*kCap*kDim + c4*4;
      for (int k=kq; k<deg; k+=4){
        const float4 v = *(const float4*)(bp + (size_t)k*kDim);
        acc.x+=v.x; acc.y+=v.y; acc.z+=v.z; acc.w+=v.w;
      }
    }
    sred[ns][kq][c4] = acc;
  }
  __syncthreads();
  if (t < kNB*10){
    int ns = t/10, c4 = t - ns*10, n = nb+ns;
    float4 a0 = sred[ns][0][c4], a1 = sred[ns][1][c4];
    float4 a2 = sred[ns][2][c4], a3 = sred[ns][3][c4];
    sa[ns][c4*4+0] = (a0.x+a1.x+a2.x+a3.x)*0.25f;   // fold 1/deg = 1/4
    sa[ns][c4*4+1] = (a0.y+a1.y+a2.y+a3.y)*0.25f;
    sa[ns][c4*4+2] = (a0.z+a1.z+a2.z+a3.z)*0.25f;
    sa[ns][c4*4+3] = (a0.w+a1.w+a2.w+a3.w)*0.25f;
    float4 xv = (n < kNodes) ? *(const float4*)(x + (size_t)n*kDim + c4*4)
                             : make_float4(0.f,0.f,0.f,0.f);
    sx[ns][c4*4+0]=xv.x; sx[ns][c4*4+1]=xv.y; sx[ns][c4*4+2]=xv.z; sx[ns][c4*4+3]=xv.w;
  }
  __syncthreads();
  if (t < kNB*16){
    int ns = t>>4, w = t&15, n = nb+ns;
    const float* ap = sa[ns];
    const float* xp = sx[ns];
    float hsum = 0.f;
    #pragma unroll
    for (int u=0;u<16;++u) hsum += ap[u]*sW2s[u*16+w];
    hsum *= 0.25f;                 // 1/sqrt(16)
    float nrm = sqrtf(hsum*hsum + 1e-16f);
    float val = hsum/nrm*sspf(nrm);
    float xs[16];
    #pragma unroll
    for (int v=0;v<16;++v) xs[v] = xp[v];
    float r0 = 0.f;
    #pragma unroll
    for (int u=0;u<16;++u){
      float tacc = 0.f;
      #pragma unroll
      for (int v=0;v<16;++v) tacc += xs[v]*sR00[(u*16+v)*16+w];
      r0 += xs[u]*tacc;
    }
    float xv[24];
    #pragma unroll
    for (int c2=0;c2<24;++c2) xv[c2] = xp[16+c2];
    float r1 = 0.f;
    #pragma unroll
    for (int u=0;u<8;++u){
      #pragma unroll
      for (int v=0;v<8;++v){
        float dot = xv[u*3]*xv[v*3] + xv[u*3+1]*xv[v*3+1] + xv[u*3+2]*xv[v*3+2];
        r1 += dot*sR11[(u*8+v)*16+w];
      }
    }
    if (n < kNodes)
      out[(size_t)n*kDim + w] = val + 0.04419417382415922f*r0 + 0.05103103630798288f*r1;
  } else if (t < kNB*16 + kNB*24) {
    int t2 = t - kNB*16;
    int ns = t2/24, cc = t2 - ns*24, w = cc/3, i = cc - w*3, n = nb+ns;
    const float* ap = sa[ns] + 16;
    const float* xp = sx[ns];
    float h0=0.f,h1=0.f,h2=0.f;
    #pragma unroll
    for (int u=0;u<8;++u){
      float wv = sW2v[u*8+w];
      h0 += ap[u*3+0]*wv; h1 += ap[u*3+1]*wv; h2 += ap[u*3+2]*wv;
    }
    const float sc = 0.35355339059327373f;   // 1/sqrt(8)
    h0*=sc; h1*=sc; h2*=sc;
    float nv = sqrtf(h0*h0+h1*h1+h2*h2 + 1e-16f);
    float hi = (i==0)?h0:((i==1)?h1:h2);
    float val = hi/nv*sspf(nv);
    float xs[16];
    #pragma unroll
    for (int v=0;v<16;++v) xs[v] = xp[v];
    float xvi[8];
    #pragma unroll
    for (int v=0;v<8;++v) xvi[v] = xp[16+v*3+i];
    float racc = 0.f;
    #pragma unroll
    for (int u=0;u<16;++u){
      float tacc=0.f;
      #pragma unroll
      for (int v=0;v<8;++v) tacc += xvi[v]*sR01[(u*8+v)*8+w];
      racc += xs[u]*tacc;
    }
    #pragma unroll
    for (int u=0;u<8;++u){
      float tacc=0.f;
      #pragma unroll
      for (int v=0;v<16;++v) tacc += xs[v]*sR10[(u*16+v)*8+w];
      racc += xvi[u]*tacc;
    }
    if (n < kNodes)
      out[(size_t)n*kDim + 16 + cc] = val + 0.0625f*racc;   // inv2/sqrt(128)
  }
}

extern "C" void kernel_launch(void* const* d_in, const int* in_sizes, int n_in,
                              void* d_out, int out_size, void* d_ws, size_t ws_size,
                              hipStream_t stream){
  const float* x   = (const float*)d_in[0];
  const float* er  = (const float*)d_in[1];
  const float* esh = (const float*)d_in[2];
  const int*   esrc= (const int*)d_in[3];
  const int*   edst= (const int*)d_in[4];
  const float* W1s = (const float*)d_in[6];
  const float* W1v = (const float*)d_in[7];
  const float* Wfc = (const float*)d_in[8];
  const float* W2s = (const float*)d_in[9];
  const float* W2v = (const float*)d_in[10];
  const float* R00 = (const float*)d_in[11];
  const float* R01 = (const float*)d_in[12];
  const float* R10 = (const float*)d_in[13];
  const float* R11 = (const float*)d_in[14];
  float* out = (float*)d_out;

  // ws layout (16B-aligned blocks)
  char* wsb = (char*)d_ws;
  float* msg = (float*)wsb;                                     // 10000*96*40 f (153.6 MB)
  short* Bf  = (short*)(wsb + (size_t)kNodes*kCap*kDim*4);      // 12*64*8 bf16 (12 KB)
  int*   cnt = (int*)(Bf + 12*64*8);                            // 10,000

  k_setup<<<10, 1024, 0, stream>>>(Wfc, Bf, cnt);
  k_edge<<<kEdges/64, 256, 0, stream>>>(er, esh, esrc, edst, x, W1s, W1v, Bf, msg, cnt);
  k_node<<<(kNodes+kNB-1)/kNB, 960, 0, stream>>>(x, msg, cnt, W2s, W2v, R00, R01, R10, R11, out);
}